// Round 2
// baseline (132.806 us; speedup 1.0000x reference)
//
#include <hip/hip_runtime.h>
#include <math.h>

#define N_MELS   128
#define N_FFT    2048
#define HOP      512
#define BATCH    8
#define S_LEN    661500
#define CH       2
#define T_FRAMES 1292            // 1 + S_LEN/HOP
#define NBINS    1025            // 1 + N_FFT/2

#define ANG 0.003067961575771282f   // 2*pi/2048

// d_ws layout (byte offsets)
#define WS_WIN     0        // float[2048]   hann window
#define WS_TW      8192     // float2[2048]  W_2048^j
#define WS_WBEG    24576    // int[128]      4-aligned start bin per mel
#define WS_WTAB    25600    // float[128*64] dense zero-padded mel weights

// pw planes: [h*PW_FR + c*PW_OFF + f], h in 0..3 (4 frames), c in 0..1.
//   PW_FR = 2120 ≡ 8 (mod 32 banks) -> the 4 h-planes start at bank groups
//   0/8/16/24; PW_OFF = 1060 ≡ 4.  Max idx 3*2120+1060+1059 = 8479 < 9216.
#define PW_OFF   1060       // channel-plane stride (floats)
#define PW_FR    2120       // frame-plane stride (floats)

// Padded exchange buffer: element e in [0,2048) lives at Z[e + 2*(e>>4)].
#define ZN 2304             // float2 per buffer; two buffers = 36864 B

__device__ __forceinline__ float2 cadd(float2 a, float2 b){ return make_float2(a.x+b.x, a.y+b.y); }
__device__ __forceinline__ float2 csub(float2 a, float2 b){ return make_float2(a.x-b.x, a.y-b.y); }
__device__ __forceinline__ float2 cmul(float2 a, float2 b){ return make_float2(a.x*b.x - a.y*b.y, a.x*b.y + a.y*b.x); }
__device__ __forceinline__ float2 cnegi(float2 z){ return make_float2(z.y, -z.x); }   // -i*z

// radix-8 DIF butterfly: b[k] = sum_j a[j] * W8^{jk}, W8 = exp(-i*pi/4)
__device__ __forceinline__ void bfly8(const float2* a, float2* b) {
    const float C = 0.70710678118654752f;
    float2 e0=cadd(a[0],a[4]), e1=cadd(a[1],a[5]), e2=cadd(a[2],a[6]), e3=cadd(a[3],a[7]);
    float2 o0=csub(a[0],a[4]), o1=csub(a[1],a[5]), o2=csub(a[2],a[6]), o3=csub(a[3],a[7]);
    float2 t1 = make_float2(C*(o1.x+o1.y), C*(o1.y-o1.x));      // o1*W8^1
    float2 t2 = make_float2(o2.y, -o2.x);                        // o2*W8^2 (-i)
    float2 t3 = make_float2(C*(o3.y-o3.x), -C*(o3.x+o3.y));      // o3*W8^3
    {
        float2 s0=cadd(e0,e2), d0=csub(e0,e2);
        float2 s1=cadd(e1,e3), d1=csub(e1,e3);
        b[0]=cadd(s0,s1); b[4]=csub(s0,s1);
        b[2]=cadd(d0,cnegi(d1)); b[6]=csub(d0,cnegi(d1));
    }
    {
        float2 s0=cadd(o0,t2), d0=csub(o0,t2);
        float2 s1=cadd(t1,t3), d1=csub(t1,t3);
        b[1]=cadd(s0,s1); b[5]=csub(s0,s1);
        b[3]=cadd(d0,cnegi(d1)); b[7]=csub(d0,cnegi(d1));
    }
}

// Both frames: bfly8 + shared incremental twiddle chain, results back into rA/rB.
__device__ __forceinline__ void stage_pair(float2* rA, float2* rB, float2 w1) {
    float2 bqA[8], bqB[8];
    bfly8(rA, bqA);
    bfly8(rB, bqB);
    rA[0] = bqA[0]; rB[0] = bqB[0];
    float2 wk = w1;
    #pragma unroll
    for (int k = 1; k < 8; ++k) {
        rA[k] = cmul(wk, bqA[k]);
        rB[k] = cmul(wk, bqB[k]);
        wk = cmul(wk, w1);
    }
}

// stage-4 radix-4 (s=512, twiddle-free) butterfly
__device__ __forceinline__ void bf4(const float2* I, float2* O) {
    float2 apc=cadd(I[0],I[2]), amc=csub(I[0],I[2]);
    float2 bpd=cadd(I[1],I[3]), bmd=csub(I[1],I[3]);
    O[0]=cadd(apc,bpd); O[1]=cadd(amc,cnegi(bmd));
    O[2]=csub(apc,bpd); O[3]=csub(amc,cnegi(bmd));
}

// two-channel untangle: (|A|^2, |B|^2) for Zf, Zm = Z[N-f]
__device__ __forceinline__ float2 upair(float2 Zf, float2 Zm) {
    float br = Zm.x, bi = -Zm.y;
    float e0 = Zf.x + br, e1 = Zf.y + bi;
    float o0 = Zf.y - bi, o1 = Zf.x - br;
    return make_float2(0.25f*(e0*e0 + e1*e1), 0.25f*(o0*o0 + o1*o1));
}

// Full 2048-pt FFT for TWO frames concurrently, A through Zq0, B through Zq1.
// 2 barriers per stage (vs 4 with a shared buffer). Ends with the stage-4
// gather (A1/A2, B1/B2) and a trailing sync, after which both buffers are
// free for reuse.
__device__ __forceinline__ void fft2048_pair(
        float2* rA, float2* rB, float4* Zq0, float4* Zq1,
        const float2* tw, int tid, int rb, int rb2,
        float2* A1, float2* A2, float2* B1, float2* B2)
{
    float2* Z0 = (float2*)Zq0;
    float2* Z1 = (float2*)Zq1;

    // Stage 1: radix-8, s=1. Outputs e = 8*tid + k (b128 writes).
    stage_pair(rA, rB, tw[tid]);
    {
        const int f4 = 4*tid + (tid>>1);          // float4 index of OFFE(8*tid)/2
        #pragma unroll
        for (int j = 0; j < 4; ++j) {
            Zq0[f4+j] = make_float4(rA[2*j].x, rA[2*j].y, rA[2*j+1].x, rA[2*j+1].y);
            Zq1[f4+j] = make_float4(rB[2*j].x, rB[2*j].y, rB[2*j+1].x, rB[2*j+1].y);
        }
        __syncthreads();
        #pragma unroll
        for (int k = 0; k < 8; ++k) { rA[k] = Z0[rb + 288*k]; rB[k] = Z1[rb + 288*k]; }
        __syncthreads();
    }

    // Stage 2: radix-8, s=8. Outputs e = q + 64a + 8k.
    stage_pair(rA, rB, tw[tid & ~7]);
    {
        const int base = (tid & 7) + 72*(tid >> 3);
        #pragma unroll
        for (int k = 0; k < 8; ++k) {
            Z0[base + 8*k + 2*(k>>1)] = rA[k];
            Z1[base + 8*k + 2*(k>>1)] = rB[k];
        }
        __syncthreads();
        #pragma unroll
        for (int k = 0; k < 8; ++k) { rA[k] = Z0[rb + 288*k]; rB[k] = Z1[rb + 288*k]; }
        __syncthreads();
    }

    // Stage 3: radix-8, s=64. Outputs e = q + 512a + 64k. Then the stage-4
    // butterfly-pair gather (b1 = tid, b2 = 512-tid).
    stage_pair(rA, rB, tw[tid & ~63]);
    {
        const int q = tid & 63;
        const int base = q + 2*(q>>4) + 576*(tid >> 6);
        #pragma unroll
        for (int k = 0; k < 8; ++k) {
            Z0[base + 72*k] = rA[k];
            Z1[base + 72*k] = rB[k];
        }
        __syncthreads();
        #pragma unroll
        for (int k = 0; k < 4; ++k) {
            A1[k] = Z0[rb + 576*k]; A2[k] = Z0[rb2 + 576*k];
            B1[k] = Z1[rb + 576*k]; B2[k] = Z1[rb2 + 576*k];
        }
        __syncthreads();
    }
}

// stage-4 + untangle, result kept in registers (5 float2, static indices)
__device__ __forceinline__ void finish_frame(const float2* F1, const float2* F2,
                                             int tid, float2* p)
{
    float2 O1[4], O2[4];
    bf4(F1, O1); bf4(F2, O2);
    if (tid == 0) {
        p[0] = upair(O1[0], O1[0]);
        p[1] = upair(O1[1], O1[3]);
        p[2] = upair(O1[2], O1[2]);
        p[3] = upair(O2[0], O2[3]);
        p[4] = upair(O2[1], O2[2]);
    } else {
        p[0] = upair(O1[0], O2[3]);
        p[1] = upair(O1[1], O2[2]);
        p[2] = upair(O2[0], O1[3]);
        p[3] = upair(O2[1], O1[2]);
        p[4] = make_float2(0.0f, 0.0f);
    }
}

__device__ __forceinline__ void store_frame(float* pwf, int tid, const float2* p)
{
    if (tid == 0) {
        pwf[0]    = p[0].x; pwf[PW_OFF+0]    = p[0].y;
        pwf[512]  = p[1].x; pwf[PW_OFF+512]  = p[1].y;
        pwf[1024] = p[2].x; pwf[PW_OFF+1024] = p[2].y;
        pwf[256]  = p[3].x; pwf[PW_OFF+256]  = p[3].y;
        pwf[768]  = p[4].x; pwf[PW_OFF+768]  = p[4].y;
    } else {
        pwf[tid]      = p[0].x; pwf[PW_OFF+tid]      = p[0].y;
        pwf[tid+512]  = p[1].x; pwf[PW_OFF+tid+512]  = p[1].y;
        pwf[512-tid]  = p[2].x; pwf[PW_OFF+512-tid]  = p[2].y;
        pwf[1024-tid] = p[3].x; pwf[PW_OFF+1024-tid] = p[3].y;
    }
}

// --- setup: blocks 0..7 build tables; blocks 8..135: mel weight rows ---
__global__ __launch_bounds__(256) void setup_kernel(
        const float* __restrict__ fb, float* __restrict__ ws) {
    int blk = blockIdx.x;
    if (blk < 8) {
        int i = blk * 256 + threadIdx.x;
        float*  win = ws;
        float2* tw  = (float2*)((char*)ws + WS_TW);
        win[i] = 0.5f - 0.5f * cosf(ANG * (float)i);
        float sn, cs; sincosf(-ANG * (float)i, &sn, &cs);
        tw[i] = make_float2(cs, sn);
    } else {
        int m = blk - 8;
        int lane = threadIdx.x;
        if (lane < 64) {
            int*   wbeg = (int*)((char*)ws + WS_WBEG);
            float* wtab = (float*)((char*)ws + WS_WTAB);
            const float* row = fb + m * NBINS;
            int s = NBINS;
            for (int f = lane; f < NBINS; f += 64)
                if (row[f] != 0.0f && f < s) s = f;
            #pragma unroll
            for (int o = 32; o; o >>= 1) s = min(s, __shfl_xor(s, o));
            int a0 = s & ~3;              // 4-aligned start; slaney span<=54+3<64
            if (a0 > NBINS - 1) a0 = (NBINS - 1) & ~3;
            if (lane == 0) wbeg[m] = a0;
            int f = a0 + lane;
            wtab[(m << 6) + lane] = (f < NBINS) ? row[f] : 0.0f;
        }
    }
}

// --- main: 4 frames per block through 2 exchange buffers ---
// 36864 B LDS -> 4 blocks/CU (16 waves); launch_bounds(256,4) caps VGPR=128.
// Barriers: 13 per block for 4 frames (was 26).
__global__ __launch_bounds__(256, 4) void mel_spec_kernel(
        const float* __restrict__ x, const float* __restrict__ fb,
        const float* __restrict__ ws, float* __restrict__ out) {
    __shared__ float4 Zq[ZN];            // 2 buffers x 18432 B = 36864 B
    float4* Zq0 = Zq;
    float4* Zq1 = Zq + (ZN/2);
    float*  pwb = (float*)Zq;            // pw planes: [h*2120 + c*1060 + f]

    const float*  win  = ws;
    const float2* tw   = (const float2*)((const char*)ws + WS_TW);
    const int*    wbeg = (const int*)((const char*)ws + WS_WBEG);
    const float*  wtab = (const float*)((const char*)ws + WS_WTAB);

    const int tid = threadIdx.x;
    const int bid = blockIdx.x;
    const int b   = bid & 7;              // XCD-contiguous: one batch item per XCD
    const int t0  = (bid >> 3) * 4;       // frames t0 .. t0+3

    const float2* xb = (const float2*)x + (size_t)b * S_LEN;
    const int tb0 = t0*HOP - (N_FFT/2);   // frame h starts at tb0 + 512h

    const int rb  = tid + 2*(tid>>4);     // OFFE(tid); +288 per 256 elements
    const int b2  = (tid == 0) ? 256 : 512 - tid;
    const int rb2 = b2 + 2*(b2>>4);

    // ---- Input: 4 frames overlap; sample (tid,k) of frame h is v[k+2h].
    // 14 float2 loads cover all 3584 distinct samples (vs 8 per frame).
    // Reflection acts on the shared sample index, so v-sharing holds in the
    // slow path too.
    float2 v[14];
    float  wv[8];
    if (tb0 >= 0 && tb0 + (3584 - 1) < S_LEN) {
        #pragma unroll
        for (int k = 0; k < 14; ++k) v[k] = xb[tb0 + tid + 256*k];
    } else {
        #pragma unroll
        for (int k = 0; k < 14; ++k) {
            int s = tb0 + tid + 256*k;
            if (s < 0) s = -s; else if (s >= S_LEN) s = 2*S_LEN - 2 - s;
            v[k] = xb[s];
        }
    }
    #pragma unroll
    for (int k = 0; k < 8; ++k) wv[k] = win[tid + 256*k];

    float2 rA[8], rB[8];
    float2 A1[4], A2[4], B1[4], B2[4];
    float2 pA[5], pB[5], pC[5], pD[5];

    // ======== pair (A,B) = frames t0+0, t0+1
    #pragma unroll
    for (int k = 0; k < 8; ++k) {
        rA[k] = make_float2(v[k].x*wv[k],   v[k].y*wv[k]);
        rB[k] = make_float2(v[k+2].x*wv[k], v[k+2].y*wv[k]);
    }
    fft2048_pair(rA, rB, Zq0, Zq1, tw, tid, rb, rb2, A1, A2, B1, B2);
    finish_frame(A1, A2, tid, pA);
    finish_frame(B1, B2, tid, pB);

    // ======== pair (C,D) = frames t0+2, t0+3
    #pragma unroll
    for (int k = 0; k < 8; ++k) {
        rA[k] = make_float2(v[k+4].x*wv[k], v[k+4].y*wv[k]);
        rB[k] = make_float2(v[k+6].x*wv[k], v[k+6].y*wv[k]);
    }
    fft2048_pair(rA, rB, Zq0, Zq1, tw, tid, rb, rb2, A1, A2, B1, B2);
    finish_frame(A1, A2, tid, pC);
    finish_frame(B1, B2, tid, pD);

    // ======== pw planes for all 4 frames (buffers free after last sync).
    store_frame(pwb + 0*PW_FR, tid, pA);
    store_frame(pwb + 1*PW_FR, tid, pB);
    store_frame(pwb + 2*PW_FR, tid, pC);
    store_frame(pwb + 3*PW_FR, tid, pD);
    // Zero the 35-float gap [1025,1060) after each of the 8 planes so the
    // mel tail reads (up to bin 1035) hit exact zeros, not stale data.
    {
        int i = tid;
        int pl = i / 35, o = i - pl*35;
        if (i < 280) pwb[(pl>>1)*PW_FR + (pl&1)*PW_OFF + 1025 + o] = 0.0f;
        i = tid + 256;
        pl = i / 35; o = i - pl*35;
        if (i < 280) pwb[(pl>>1)*PW_FR + (pl&1)*PW_OFF + 1025 + o] = 0.0f;
    }
    __syncthreads();

    // ======== Mel projection: thread = (m, h0) handles frames h0 and h0+2,
    // sharing one weight-row load. Plane starts at bank group 8h (PW_FR≡8),
    // channel 1 at +4 (PW_OFF≡4): the lane pair and the two h's all hit
    // disjoint 4-bank groups.
    {
        int m  = tid >> 1;
        int h0 = tid & 1;
        int a0 = wbeg[m];
        const float4* wt4 = (const float4*)(wtab + (m << 6));
        const float*  q00 = pwb +  h0   *PW_FR + a0;            // h0,  ch0
        const float*  q01 = pwb +  h0   *PW_FR + PW_OFF + a0;   // h0,  ch1
        const float*  q10 = pwb + (h0+2)*PW_FR + a0;            // h0+2,ch0
        const float*  q11 = pwb + (h0+2)*PW_FR + PW_OFF + a0;   // h0+2,ch1
        float a00 = 0.0f, a01 = 0.0f, a10 = 0.0f, a11 = 0.0f;
        #pragma unroll
        for (int j = 0; j < 16; ++j) {
            float4 w4 = wt4[j];
            float4 r0 = *(const float4*)(q00 + 4*j);
            float4 r1 = *(const float4*)(q01 + 4*j);
            float4 r2 = *(const float4*)(q10 + 4*j);
            float4 r3 = *(const float4*)(q11 + 4*j);
            a00 += w4.x*r0.x + w4.y*r0.y + w4.z*r0.z + w4.w*r0.w;
            a01 += w4.x*r1.x + w4.y*r1.y + w4.z*r1.z + w4.w*r1.w;
            a10 += w4.x*r2.x + w4.y*r2.y + w4.z*r2.z + w4.w*r2.w;
            a11 += w4.x*r3.x + w4.y*r3.y + w4.z*r3.z + w4.w*r3.w;
        }
        size_t base = (((size_t)b * N_MELS + m) * T_FRAMES + t0 + h0) * CH;
        *(float2*)(out + base)         = make_float2(a00, a01);
        *(float2*)(out + base + 2*CH)  = make_float2(a10, a11);
    }
}

extern "C" void kernel_launch(void* const* d_in, const int* in_sizes, int n_in,
                              void* d_out, int out_size, void* d_ws, size_t ws_size,
                              hipStream_t stream) {
    const float* x  = (const float*)d_in[0];
    const float* fb = (const float*)d_in[1];
    float* out = (float*)d_out;
    float* ws  = (float*)d_ws;

    setup_kernel<<<8 + N_MELS, 256, 0, stream>>>(fb, ws);
    mel_spec_kernel<<<BATCH * (T_FRAMES/4), 256, 0, stream>>>(x, fb, ws, out);
}

// Round 3
// 121.561 us; speedup vs baseline: 1.0925x; 1.0925x over previous
//
#include <hip/hip_runtime.h>
#include <math.h>

#define N_MELS   128
#define N_FFT    2048
#define HOP      512
#define BATCH    8
#define S_LEN    661500
#define CH       2
#define T_FRAMES 1292            // 1 + S_LEN/HOP
#define NBINS    1025            // 1 + N_FFT/2

#define ANG 0.003067961575771282f   // 2*pi/2048

// d_ws layout (byte offsets)
#define WS_WIN     0        // float[2048]   hann window
#define WS_TW      8192     // float2[2048]  W_2048^j
#define WS_WBEG    24576    // int[128]      4-aligned start bin per mel
#define WS_WN4     25088    // int[128]      float4 iteration count per mel
#define WS_WTAB    25600    // float[128*64] dense zero-padded mel weights

// pw planes: [h*PW_FR + c*PW_OFF + f]. Strides chosen so the (m,h) lane
// pairs in the mel loop land on DISJOINT bank groups:
//   PW_FR  = 2120 ≡ 8  (mod 32 banks), PW_OFF = 1060 ≡ 4 (mod 32 banks).
// Both are multiples of 4 so float4 reads stay 16B-aligned.
// Max float index = 2120 + 1060 + 1059 = 4239 < 4608 (buffer floats).
#define PW_OFF   1060       // channel-plane stride (floats)
#define PW_FR    2120       // frame-plane stride (floats)

// Full padded buffer: element e in [0,2048) lives at Z2[e + 2*(e>>4)].
#define ZN 2304             // float2 count = 2048 + 2*128 -> 18432 B

__device__ __forceinline__ float2 cadd(float2 a, float2 b){ return make_float2(a.x+b.x, a.y+b.y); }
__device__ __forceinline__ float2 csub(float2 a, float2 b){ return make_float2(a.x-b.x, a.y-b.y); }
__device__ __forceinline__ float2 cmul(float2 a, float2 b){ return make_float2(a.x*b.x - a.y*b.y, a.x*b.y + a.y*b.x); }
__device__ __forceinline__ float2 cnegi(float2 z){ return make_float2(z.y, -z.x); }   // -i*z

// radix-8 DIF butterfly: b[k] = sum_j a[j] * W8^{jk}, W8 = exp(-i*pi/4)
__device__ __forceinline__ void bfly8(const float2* a, float2* b) {
    const float C = 0.70710678118654752f;
    float2 e0=cadd(a[0],a[4]), e1=cadd(a[1],a[5]), e2=cadd(a[2],a[6]), e3=cadd(a[3],a[7]);
    float2 o0=csub(a[0],a[4]), o1=csub(a[1],a[5]), o2=csub(a[2],a[6]), o3=csub(a[3],a[7]);
    float2 t1 = make_float2(C*(o1.x+o1.y), C*(o1.y-o1.x));      // o1*W8^1
    float2 t2 = make_float2(o2.y, -o2.x);                        // o2*W8^2 (-i)
    float2 t3 = make_float2(C*(o3.y-o3.x), -C*(o3.x+o3.y));      // o3*W8^3
    {
        float2 s0=cadd(e0,e2), d0=csub(e0,e2);
        float2 s1=cadd(e1,e3), d1=csub(e1,e3);
        b[0]=cadd(s0,s1); b[4]=csub(s0,s1);
        b[2]=cadd(d0,cnegi(d1)); b[6]=csub(d0,cnegi(d1));
    }
    {
        float2 s0=cadd(o0,t2), d0=csub(o0,t2);
        float2 s1=cadd(t1,t3), d1=csub(t1,t3);
        b[1]=cadd(s0,s1); b[5]=csub(s0,s1);
        b[3]=cadd(d0,cnegi(d1)); b[7]=csub(d0,cnegi(d1));
    }
}

// Both frames: bfly8 + shared twiddle product TREE (depth 3, was a 7-deep
// serial chain), results back into rA/rB.
__device__ __forceinline__ void stage_pair(float2* rA, float2* rB, float2 w1) {
    float2 bqA[8], bqB[8];
    bfly8(rA, bqA);
    bfly8(rB, bqB);
    float2 w2 = cmul(w1, w1);
    float2 w3 = cmul(w2, w1);
    float2 w4 = cmul(w2, w2);
    float2 w5 = cmul(w4, w1);
    float2 w6 = cmul(w4, w2);
    float2 w7 = cmul(w4, w3);
    rA[0] = bqA[0];           rB[0] = bqB[0];
    rA[1] = cmul(w1, bqA[1]); rB[1] = cmul(w1, bqB[1]);
    rA[2] = cmul(w2, bqA[2]); rB[2] = cmul(w2, bqB[2]);
    rA[3] = cmul(w3, bqA[3]); rB[3] = cmul(w3, bqB[3]);
    rA[4] = cmul(w4, bqA[4]); rB[4] = cmul(w4, bqB[4]);
    rA[5] = cmul(w5, bqA[5]); rB[5] = cmul(w5, bqB[5]);
    rA[6] = cmul(w6, bqA[6]); rB[6] = cmul(w6, bqB[6]);
    rA[7] = cmul(w7, bqA[7]); rB[7] = cmul(w7, bqB[7]);
}

// stage-4 radix-4 (s=512, twiddle-free) butterfly
__device__ __forceinline__ void bf4(const float2* I, float2* O) {
    float2 apc=cadd(I[0],I[2]), amc=csub(I[0],I[2]);
    float2 bpd=cadd(I[1],I[3]), bmd=csub(I[1],I[3]);
    O[0]=cadd(apc,bpd); O[1]=cadd(amc,cnegi(bmd));
    O[2]=csub(apc,bpd); O[3]=csub(amc,cnegi(bmd));
}

// two-channel untangle: (|A|^2, |B|^2) for Zf, Zm = Z[N-f]
__device__ __forceinline__ float2 upair(float2 Zf, float2 Zm) {
    float br = Zm.x, bi = -Zm.y;
    float e0 = Zf.x + br, e1 = Zf.y + bi;
    float o0 = Zf.y - bi, o1 = Zf.x - br;
    return make_float2(0.25f*(e0*e0 + e1*e1), 0.25f*(o0*o0 + o1*o1));
}

// --- setup: blocks 0..7 build tables; blocks 8..135: mel weight rows ---
__global__ __launch_bounds__(256) void setup_kernel(
        const float* __restrict__ fb, float* __restrict__ ws) {
    int blk = blockIdx.x;
    if (blk < 8) {
        int i = blk * 256 + threadIdx.x;
        float*  win = ws;
        float2* tw  = (float2*)((char*)ws + WS_TW);
        win[i] = 0.5f - 0.5f * cosf(ANG * (float)i);
        float sn, cs; sincosf(-ANG * (float)i, &sn, &cs);
        tw[i] = make_float2(cs, sn);
    } else {
        int m = blk - 8;
        int lane = threadIdx.x;
        if (lane < 64) {
            int*   wbeg = (int*)((char*)ws + WS_WBEG);
            int*   wn4  = (int*)((char*)ws + WS_WN4);
            float* wtab = (float*)((char*)ws + WS_WTAB);
            const float* row = fb + m * NBINS;
            int s = NBINS;      // first nonzero bin
            int e = 0;          // last nonzero bin
            for (int f = lane; f < NBINS; f += 64) {
                if (row[f] != 0.0f) { if (f < s) s = f; if (f > e) e = f; }
            }
            #pragma unroll
            for (int o = 32; o; o >>= 1) {
                s = min(s, __shfl_xor(s, o));
                e = max(e, __shfl_xor(e, o));
            }
            int a0 = s & ~3;              // 4-aligned start; slaney span<=54+3<64
            if (a0 > NBINS - 1) a0 = (NBINS - 1) & ~3;
            int n4 = (e - a0 + 4) >> 2;   // ceil((e-a0+1)/4)
            if (n4 < 1) n4 = 1;
            if (n4 > 16) n4 = 16;
            if (lane == 0) { wbeg[m] = a0; wn4[m] = n4; }
            int f = a0 + lane;
            wtab[(m << 6) + lane] = (f < NBINS) ? row[f] : 0.0f;
        }
    }
}

// --- main: 2 frames per block; full-buffer exchange, frames alternate ---
// 18432 B LDS -> 8 blocks/CU (R2 lesson: bigger LDS collapses occupancy).
__global__ __launch_bounds__(256, 8) void mel_spec_kernel(
        const float* __restrict__ x, const float* __restrict__ fb,
        const float* __restrict__ ws, float* __restrict__ out) {
    __shared__ float4 Zq[ZN/2];          // 18432 B, one full padded buffer
    float2* Z2  = (float2*)Zq;
    float*  pwb = (float*)Zq;            // pw planes: [h*2120 + c*1060 + f]

    const float*  win  = ws;
    const float2* tw   = (const float2*)((const char*)ws + WS_TW);
    const int*    wbeg = (const int*)((const char*)ws + WS_WBEG);
    const int*    wn4  = (const int*)((const char*)ws + WS_WN4);
    const float*  wtab = (const float*)((const char*)ws + WS_WTAB);

    const int tid = threadIdx.x;
    const int bid = blockIdx.x;
    const int b   = bid & 7;              // XCD-contiguous: one batch item per XCD
    const int t0  = (bid >> 3) * 2;       // frames t0, t0+1

    const float2* xb = (const float2*)x + (size_t)b * S_LEN;
    const int tbA = t0*HOP - (N_FFT/2);
    const int tbB = tbA + HOP;

    float2 rA[8], rB[8];
    const int rb = tid + 2*(tid>>4);      // OFFE(tid); +288 per 256 elements

    // ---- Input: frames overlap by 1536 samples (HOP=512=2*256), so
    // frame-B element (tid,k) == frame-A element (tid,k+2). Fast path loads
    // 10 float2/thread instead of 16.
    if (tbA >= 0 && tbB + (N_FFT - 1) < S_LEN) {
        float2 v[10];
        #pragma unroll
        for (int k = 0; k < 10; ++k) v[k] = xb[tbA + tid + 256*k];
        #pragma unroll
        for (int k = 0; k < 8; ++k) {
            float w = win[tid + 256*k];
            rA[k] = make_float2(v[k].x*w,   v[k].y*w);
            rB[k] = make_float2(v[k+2].x*w, v[k+2].y*w);
        }
    } else {
        #pragma unroll
        for (int k = 0; k < 8; ++k) {
            int n  = tid + 256*k;
            float w = win[n];
            int sA = tbA + n;
            if (sA < 0) sA = -sA; else if (sA >= S_LEN) sA = 2*S_LEN - 2 - sA;
            float2 vA = xb[sA];
            rA[k] = make_float2(vA.x*w, vA.y*w);
            int sB = tbB + n;
            if (sB < 0) sB = -sB; else if (sB >= S_LEN) sB = 2*S_LEN - 2 - sB;
            float2 vB = xb[sB];
            rB[k] = make_float2(vB.x*w, vB.y*w);
        }
    }

    // ======== Stage 1: radix-8, s=1. Outputs e = 8*tid + k (b128 writes).
    stage_pair(rA, rB, tw[tid]);
    {
        const int f4 = 4*tid + (tid>>1);          // float4 index of OFFE(8*tid)/2
        #pragma unroll
        for (int j = 0; j < 4; ++j)
            Zq[f4+j] = make_float4(rA[2*j].x, rA[2*j].y, rA[2*j+1].x, rA[2*j+1].y);
        __syncthreads();
        #pragma unroll
        for (int k = 0; k < 8; ++k) rA[k] = Z2[rb + 288*k];
        __syncthreads();
        #pragma unroll
        for (int j = 0; j < 4; ++j)
            Zq[f4+j] = make_float4(rB[2*j].x, rB[2*j].y, rB[2*j+1].x, rB[2*j+1].y);
        __syncthreads();
        #pragma unroll
        for (int k = 0; k < 8; ++k) rB[k] = Z2[rb + 288*k];
        __syncthreads();
    }

    // ======== Stage 2: radix-8, s=8. Outputs e = q + 64a + 8k.
    stage_pair(rA, rB, tw[tid & ~7]);
    {
        const int base = (tid & 7) + 72*(tid >> 3);
        #pragma unroll
        for (int k = 0; k < 8; ++k) Z2[base + 8*k + 2*(k>>1)] = rA[k];
        __syncthreads();
        #pragma unroll
        for (int k = 0; k < 8; ++k) rA[k] = Z2[rb + 288*k];
        __syncthreads();
        #pragma unroll
        for (int k = 0; k < 8; ++k) Z2[base + 8*k + 2*(k>>1)] = rB[k];
        __syncthreads();
        #pragma unroll
        for (int k = 0; k < 8; ++k) rB[k] = Z2[rb + 288*k];
        __syncthreads();
    }

    // ======== Stage 3: radix-8, s=64. Outputs e = q + 512a + 64k.
    stage_pair(rA, rB, tw[tid & ~63]);
    // Stage-4 butterfly pair: b1 = tid, b2 = 512-tid (tid=0 -> {0,256}).
    const int b2  = (tid == 0) ? 256 : 512 - tid;
    const int rb2 = b2 + 2*(b2>>4);
    float2 A1[4], A2[4], B1[4], B2[4];
    {
        const int q = tid & 63;
        const int base = q + 2*(q>>4) + 576*(tid >> 6);
        #pragma unroll
        for (int k = 0; k < 8; ++k) Z2[base + 72*k] = rA[k];
        __syncthreads();
        #pragma unroll
        for (int k = 0; k < 4; ++k) { A1[k] = Z2[rb + 576*k]; A2[k] = Z2[rb2 + 576*k]; }
        __syncthreads();
        #pragma unroll
        for (int k = 0; k < 8; ++k) Z2[base + 72*k] = rB[k];
        __syncthreads();
        #pragma unroll
        for (int k = 0; k < 4; ++k) { B1[k] = Z2[rb + 576*k]; B2[k] = Z2[rb2 + 576*k]; }
        __syncthreads();
    }

    // ======== Stage 4 + untangle, straight-line per frame (registers only,
    // then pw-plane writes into Zq; all Zq reads fenced above).
    // Also zero the 35-float gap [1025,1060) after each plane so the mel
    // loop's tail reads (up to bin 1027 with the short loop) hit exact zeros.
    if (tid < 140) {
        int p = tid / 35;
        int o = tid - p * 35;
        pwb[(p>>1)*PW_FR + (p&1)*PW_OFF + 1025 + o] = 0.0f;
    }
    {
        float2 O1[4], O2[4];
        bf4(A1, O1); bf4(A2, O2);
        float* pwf = pwb;                          // frame A planes (h=0)
        if (tid == 0) {
            float2 p;
            p = upair(O1[0], O1[0]); pwf[0]    = p.x; pwf[PW_OFF+0]    = p.y;
            p = upair(O1[1], O1[3]); pwf[512]  = p.x; pwf[PW_OFF+512]  = p.y;
            p = upair(O1[2], O1[2]); pwf[1024] = p.x; pwf[PW_OFF+1024] = p.y;
            p = upair(O2[0], O2[3]); pwf[256]  = p.x; pwf[PW_OFF+256]  = p.y;
            p = upair(O2[1], O2[2]); pwf[768]  = p.x; pwf[PW_OFF+768]  = p.y;
        } else {
            float2 p;
            p = upair(O1[0], O2[3]); pwf[tid]      = p.x; pwf[PW_OFF+tid]      = p.y;
            p = upair(O1[1], O2[2]); pwf[tid+512]  = p.x; pwf[PW_OFF+tid+512]  = p.y;
            p = upair(O2[0], O1[3]); pwf[512-tid]  = p.x; pwf[PW_OFF+512-tid]  = p.y;
            p = upair(O2[1], O1[2]); pwf[1024-tid] = p.x; pwf[PW_OFF+1024-tid] = p.y;
        }
    }
    {
        float2 O1[4], O2[4];
        bf4(B1, O1); bf4(B2, O2);
        float* pwf = pwb + PW_FR;                  // frame B planes (h=1)
        if (tid == 0) {
            float2 p;
            p = upair(O1[0], O1[0]); pwf[0]    = p.x; pwf[PW_OFF+0]    = p.y;
            p = upair(O1[1], O1[3]); pwf[512]  = p.x; pwf[PW_OFF+512]  = p.y;
            p = upair(O1[2], O1[2]); pwf[1024] = p.x; pwf[PW_OFF+1024] = p.y;
            p = upair(O2[0], O2[3]); pwf[256]  = p.x; pwf[PW_OFF+256]  = p.y;
            p = upair(O2[1], O2[2]); pwf[768]  = p.x; pwf[PW_OFF+768]  = p.y;
        } else {
            float2 p;
            p = upair(O1[0], O2[3]); pwf[tid]      = p.x; pwf[PW_OFF+tid]      = p.y;
            p = upair(O1[1], O2[2]); pwf[tid+512]  = p.x; pwf[PW_OFF+tid+512]  = p.y;
            p = upair(O2[0], O1[3]); pwf[512-tid]  = p.x; pwf[PW_OFF+512-tid]  = p.y;
            p = upair(O2[1], O1[2]); pwf[1024-tid] = p.x; pwf[PW_OFF+1024-tid] = p.y;
        }
    }
    __syncthreads();

    // ======== Mel projection: thread = (m, frame h); both channels -> float2.
    // Variable-length loop: slaney filters span ~5..57 bins, so wn4[m] is
    // 2..15 float4 iterations instead of the dense 16 -- per-wave max (m is
    // wave-contiguous) is ~3/4/8/15, halving mel VALU + LDS reads on average.
    {
        int m  = tid >> 1;
        int h  = tid & 1;                      // frame t0+h
        int a0 = wbeg[m];
        int n4 = wn4[m];
        const float4* wt4 = (const float4*)(wtab + (m << 6));
        const float4* q0  = (const float4*)(pwb + h*PW_FR + a0);           // ch0
        const float4* q1  = (const float4*)(pwb + h*PW_FR + PW_OFF + a0);  // ch1
        float acc0 = 0.0f, acc1 = 0.0f;
        for (int j = 0; j < n4; ++j) {
            float4 w4 = wt4[j];
            float4 r0 = q0[j];
            float4 r1 = q1[j];
            acc0 += w4.x*r0.x + w4.y*r0.y + w4.z*r0.z + w4.w*r0.w;
            acc1 += w4.x*r1.x + w4.y*r1.y + w4.z*r1.z + w4.w*r1.w;
        }
        size_t base = (((size_t)b * N_MELS + m) * T_FRAMES + t0 + h) * CH;
        *(float2*)(out + base) = make_float2(acc0, acc1);
    }
}

extern "C" void kernel_launch(void* const* d_in, const int* in_sizes, int n_in,
                              void* d_out, int out_size, void* d_ws, size_t ws_size,
                              hipStream_t stream) {
    const float* x  = (const float*)d_in[0];
    const float* fb = (const float*)d_in[1];
    float* out = (float*)d_out;
    float* ws  = (float*)d_ws;

    setup_kernel<<<8 + N_MELS, 256, 0, stream>>>(fb, ws);
    mel_spec_kernel<<<BATCH * (T_FRAMES/2), 256, 0, stream>>>(x, fb, ws, out);
}

// Round 4
// 120.510 us; speedup vs baseline: 1.1020x; 1.0087x over previous
//
#include <hip/hip_runtime.h>
#include <math.h>

#define N_MELS   128
#define N_FFT    2048
#define HOP      512
#define BATCH    8
#define S_LEN    661500
#define CH       2
#define T_FRAMES 1292            // 1 + S_LEN/HOP
#define NBINS    1025            // 1 + N_FFT/2

#define ANG 0.003067961575771282f   // 2*pi/2048

// d_ws layout (byte offsets)
#define WS_WIN     0        // float[2048]   hann window
#define WS_TW      8192     // float2[2048]  W_2048^j
#define WS_WBEG    24576    // int[128]      4-aligned start bin per mel
#define WS_WN4     25088    // int[128]      float4 iteration count per mel
#define WS_WTAB    25600    // float[128*64] dense zero-padded mel weights

// pw planes: [h*PW_FR + c*PW_OFF + f]. PW_FR ≡ 8, PW_OFF ≡ 4 (mod 32 banks)
// so the (m,h) lane pairs in the mel loop hit disjoint bank groups.
#define PW_OFF   1060       // channel-plane stride (floats)
#define PW_FR    2120       // frame-plane stride (floats)

// Full padded buffer: element e in [0,2048) lives at Z2[e + 2*(e>>4)].
#define ZN 2304             // float2 count = 2048 + 2*128 -> 18432 B

// Native 2-vector float: arithmetic on this type maps to gfx950 packed-FP32
// VOP3P (v_pk_add_f32 / v_pk_mul_f32 / v_pk_fma_f32 with op_sel/neg
// modifiers) -- 2x issue rate vs the scalar v_add/v_fma the float2 struct
// math compiles to. Swizzles (.yx/.xx/.yy) and lane negs fold into the
// VOP3P modifiers.
typedef float vf2 __attribute__((ext_vector_type(2)));

__device__ __forceinline__ vf2 cadd(vf2 a, vf2 b){ return a + b; }        // v_pk_add
__device__ __forceinline__ vf2 csub(vf2 a, vf2 b){ return a - b; }        // v_pk_add(neg)
__device__ __forceinline__ vf2 cnegi(vf2 z){ return (vf2){ z.y, -z.x }; } // -i*z (folds)
// (a.x*b.x - a.y*b.y, a.x*b.y + a.y*b.x) = a.xx*b + (-(a.y*b.y), a.y*b.x)
__device__ __forceinline__ vf2 cmul(vf2 a, vf2 b){
    vf2 t = a.yy * b.yx;                 // v_pk_mul
    vf2 s = (vf2){ -t.x, t.y };          // neg_lo, folds into the fma
    return a.xx * b + s;                 // v_pk_fma
}

// radix-8 DIF butterfly: b[k] = sum_j a[j] * W8^{jk}, W8 = exp(-i*pi/4)
__device__ __forceinline__ void bfly8(const vf2* a, vf2* b) {
    const float C = 0.70710678118654752f;
    vf2 e0=a[0]+a[4], e1=a[1]+a[5], e2=a[2]+a[6], e3=a[3]+a[7];
    vf2 o0=a[0]-a[4], o1=a[1]-a[5], o2=a[2]-a[6], o3=a[3]-a[7];
    vf2 t1 = (o1 + cnegi(o1)) * C;       // o1*W8^1 = C*(o1.x+o1.y, o1.y-o1.x)
    vf2 t2 = cnegi(o2);                  // o2*W8^2
    vf2 t3 = (cnegi(o3) - o3) * C;       // o3*W8^3 = C*(o3.y-o3.x, -(o3.x+o3.y))
    {
        vf2 s0=e0+e2, d0=e0-e2;
        vf2 s1=e1+e3, d1=e1-e3;
        b[0]=s0+s1; b[4]=s0-s1;
        vf2 nd1=cnegi(d1);
        b[2]=d0+nd1; b[6]=d0-nd1;
    }
    {
        vf2 s0=o0+t2, d0=o0-t2;
        vf2 s1=t1+t3, d1=t1-t3;
        b[1]=s0+s1; b[5]=s0-s1;
        vf2 nd1=cnegi(d1);
        b[3]=d0+nd1; b[7]=d0-nd1;
    }
}

// Both frames: bfly8 + shared twiddle product tree (depth 3).
__device__ __forceinline__ void stage_pair(vf2* rA, vf2* rB, vf2 w1) {
    vf2 bqA[8], bqB[8];
    bfly8(rA, bqA);
    bfly8(rB, bqB);
    vf2 w2 = cmul(w1, w1);
    vf2 w3 = cmul(w2, w1);
    vf2 w4 = cmul(w2, w2);
    vf2 w5 = cmul(w4, w1);
    vf2 w6 = cmul(w4, w2);
    vf2 w7 = cmul(w4, w3);
    rA[0] = bqA[0];           rB[0] = bqB[0];
    rA[1] = cmul(w1, bqA[1]); rB[1] = cmul(w1, bqB[1]);
    rA[2] = cmul(w2, bqA[2]); rB[2] = cmul(w2, bqB[2]);
    rA[3] = cmul(w3, bqA[3]); rB[3] = cmul(w3, bqB[3]);
    rA[4] = cmul(w4, bqA[4]); rB[4] = cmul(w4, bqB[4]);
    rA[5] = cmul(w5, bqA[5]); rB[5] = cmul(w5, bqB[5]);
    rA[6] = cmul(w6, bqA[6]); rB[6] = cmul(w6, bqB[6]);
    rA[7] = cmul(w7, bqA[7]); rB[7] = cmul(w7, bqB[7]);
}

// stage-4 radix-4 (s=512, twiddle-free) butterfly
__device__ __forceinline__ void bf4(const vf2* I, vf2* O) {
    vf2 apc=I[0]+I[2], amc=I[0]-I[2];
    vf2 bpd=I[1]+I[3], bmd=I[1]-I[3];
    vf2 nb = cnegi(bmd);
    O[0]=apc+bpd; O[1]=amc+nb;
    O[2]=apc-bpd; O[3]=amc-nb;
}

// two-channel untangle: (|A|^2, |B|^2) for Zf, Zm = Z[N-f]
__device__ __forceinline__ vf2 upair(vf2 Zf, vf2 Zm) {
    vf2 B = (vf2){ Zm.x, -Zm.y };        // conj
    vf2 e = Zf + B;                      // (e0, e1)
    vf2 d = Zf - B;                      // (o1, o0)
    vf2 ee = e * e;                      // pk_mul
    vf2 dd = d * d;
    return (vf2){ 0.25f*(ee.x + ee.y), 0.25f*(dd.x + dd.y) };
}

// --- setup: blocks 0..7 build tables; blocks 8..135: mel weight rows ---
__global__ __launch_bounds__(256) void setup_kernel(
        const float* __restrict__ fb, float* __restrict__ ws) {
    int blk = blockIdx.x;
    if (blk < 8) {
        int i = blk * 256 + threadIdx.x;
        float*  win = ws;
        float2* tw  = (float2*)((char*)ws + WS_TW);
        win[i] = 0.5f - 0.5f * cosf(ANG * (float)i);
        float sn, cs; sincosf(-ANG * (float)i, &sn, &cs);
        tw[i] = make_float2(cs, sn);
    } else {
        int m = blk - 8;
        int lane = threadIdx.x;
        if (lane < 64) {
            int*   wbeg = (int*)((char*)ws + WS_WBEG);
            int*   wn4  = (int*)((char*)ws + WS_WN4);
            float* wtab = (float*)((char*)ws + WS_WTAB);
            const float* row = fb + m * NBINS;
            int s = NBINS;      // first nonzero bin
            int e = 0;          // last nonzero bin
            for (int f = lane; f < NBINS; f += 64) {
                if (row[f] != 0.0f) { if (f < s) s = f; if (f > e) e = f; }
            }
            #pragma unroll
            for (int o = 32; o; o >>= 1) {
                s = min(s, __shfl_xor(s, o));
                e = max(e, __shfl_xor(e, o));
            }
            int a0 = s & ~3;              // 4-aligned start; slaney span<=54+3<64
            if (a0 > NBINS - 1) a0 = (NBINS - 1) & ~3;
            int n4 = (e - a0 + 4) >> 2;   // ceil((e-a0+1)/4)
            if (n4 < 1) n4 = 1;
            if (n4 > 16) n4 = 16;
            if (lane == 0) { wbeg[m] = a0; wn4[m] = n4; }
            int f = a0 + lane;
            wtab[(m << 6) + lane] = (f < NBINS) ? row[f] : 0.0f;
        }
    }
}

// --- main: 2 frames per block; full-buffer exchange, frames alternate ---
// 18432 B LDS -> 8 blocks/CU (R2 lesson: bigger LDS collapses occupancy).
__global__ __launch_bounds__(256, 8) void mel_spec_kernel(
        const float* __restrict__ x, const float* __restrict__ fb,
        const float* __restrict__ ws, float* __restrict__ out) {
    __shared__ float4 Zq[ZN/2];          // 18432 B, one full padded buffer
    vf2*   Z2  = (vf2*)Zq;
    float* pwb = (float*)Zq;             // pw planes: [h*2120 + c*1060 + f]

    const float* win  = ws;
    const vf2*   tw   = (const vf2*)((const char*)ws + WS_TW);
    const int*   wbeg = (const int*)((const char*)ws + WS_WBEG);
    const int*   wn4  = (const int*)((const char*)ws + WS_WN4);
    const float* wtab = (const float*)((const char*)ws + WS_WTAB);

    const int tid = threadIdx.x;
    const int bid = blockIdx.x;
    const int b   = bid & 7;              // XCD-contiguous: one batch item per XCD
    const int t0  = (bid >> 3) * 2;       // frames t0, t0+1

    const vf2* xb = (const vf2*)x + (size_t)b * S_LEN;
    const int tbA = t0*HOP - (N_FFT/2);
    const int tbB = tbA + HOP;

    vf2 rA[8], rB[8];
    const int rb = tid + 2*(tid>>4);      // OFFE(tid); +288 per 256 elements

    // ---- Input: frames overlap by 1536 samples (HOP=512=2*256), so
    // frame-B element (tid,k) == frame-A element (tid,k+2). Fast path loads
    // 10 vf2/thread instead of 16.
    if (tbA >= 0 && tbB + (N_FFT - 1) < S_LEN) {
        vf2 v[10];
        #pragma unroll
        for (int k = 0; k < 10; ++k) v[k] = xb[tbA + tid + 256*k];
        #pragma unroll
        for (int k = 0; k < 8; ++k) {
            float w = win[tid + 256*k];
            rA[k] = v[k]   * w;           // v_pk_mul (scalar broadcast)
            rB[k] = v[k+2] * w;
        }
    } else {
        #pragma unroll
        for (int k = 0; k < 8; ++k) {
            int n  = tid + 256*k;
            float w = win[n];
            int sA = tbA + n;
            if (sA < 0) sA = -sA; else if (sA >= S_LEN) sA = 2*S_LEN - 2 - sA;
            rA[k] = xb[sA] * w;
            int sB = tbB + n;
            if (sB < 0) sB = -sB; else if (sB >= S_LEN) sB = 2*S_LEN - 2 - sB;
            rB[k] = xb[sB] * w;
        }
    }

    // ======== Stage 1: radix-8, s=1. Outputs e = 8*tid + k (b128 writes).
    stage_pair(rA, rB, tw[tid]);
    {
        const int f4 = 4*tid + (tid>>1);          // float4 index of OFFE(8*tid)/2
        #pragma unroll
        for (int j = 0; j < 4; ++j)
            Zq[f4+j] = make_float4(rA[2*j].x, rA[2*j].y, rA[2*j+1].x, rA[2*j+1].y);
        __syncthreads();
        #pragma unroll
        for (int k = 0; k < 8; ++k) rA[k] = Z2[rb + 288*k];
        __syncthreads();
        #pragma unroll
        for (int j = 0; j < 4; ++j)
            Zq[f4+j] = make_float4(rB[2*j].x, rB[2*j].y, rB[2*j+1].x, rB[2*j+1].y);
        __syncthreads();
        #pragma unroll
        for (int k = 0; k < 8; ++k) rB[k] = Z2[rb + 288*k];
        __syncthreads();
    }

    // ======== Stage 2: radix-8, s=8. Outputs e = q + 64a + 8k.
    stage_pair(rA, rB, tw[tid & ~7]);
    {
        const int base = (tid & 7) + 72*(tid >> 3);
        #pragma unroll
        for (int k = 0; k < 8; ++k) Z2[base + 8*k + 2*(k>>1)] = rA[k];
        __syncthreads();
        #pragma unroll
        for (int k = 0; k < 8; ++k) rA[k] = Z2[rb + 288*k];
        __syncthreads();
        #pragma unroll
        for (int k = 0; k < 8; ++k) Z2[base + 8*k + 2*(k>>1)] = rB[k];
        __syncthreads();
        #pragma unroll
        for (int k = 0; k < 8; ++k) rB[k] = Z2[rb + 288*k];
        __syncthreads();
    }

    // ======== Stage 3: radix-8, s=64. Outputs e = q + 512a + 64k.
    stage_pair(rA, rB, tw[tid & ~63]);
    // Stage-4 butterfly pair: b1 = tid, b2 = 512-tid (tid=0 -> {0,256}).
    const int b2  = (tid == 0) ? 256 : 512 - tid;
    const int rb2 = b2 + 2*(b2>>4);
    vf2 A1[4], A2[4], B1[4], B2[4];
    {
        const int q = tid & 63;
        const int base = q + 2*(q>>4) + 576*(tid >> 6);
        #pragma unroll
        for (int k = 0; k < 8; ++k) Z2[base + 72*k] = rA[k];
        __syncthreads();
        #pragma unroll
        for (int k = 0; k < 4; ++k) { A1[k] = Z2[rb + 576*k]; A2[k] = Z2[rb2 + 576*k]; }
        __syncthreads();
        #pragma unroll
        for (int k = 0; k < 8; ++k) Z2[base + 72*k] = rB[k];
        __syncthreads();
        #pragma unroll
        for (int k = 0; k < 4; ++k) { B1[k] = Z2[rb + 576*k]; B2[k] = Z2[rb2 + 576*k]; }
        __syncthreads();
    }

    // ======== Stage 4 + untangle, straight-line per frame (registers only,
    // then pw-plane writes into Zq; all Zq reads fenced above).
    // Also zero the 35-float gap [1025,1060) after each plane so the mel
    // loop's tail reads (up to bin 1027 with the short loop) hit exact zeros.
    if (tid < 140) {
        int p = tid / 35;
        int o = tid - p * 35;
        pwb[(p>>1)*PW_FR + (p&1)*PW_OFF + 1025 + o] = 0.0f;
    }
    {
        vf2 O1[4], O2[4];
        bf4(A1, O1); bf4(A2, O2);
        float* pwf = pwb;                          // frame A planes (h=0)
        if (tid == 0) {
            vf2 p;
            p = upair(O1[0], O1[0]); pwf[0]    = p.x; pwf[PW_OFF+0]    = p.y;
            p = upair(O1[1], O1[3]); pwf[512]  = p.x; pwf[PW_OFF+512]  = p.y;
            p = upair(O1[2], O1[2]); pwf[1024] = p.x; pwf[PW_OFF+1024] = p.y;
            p = upair(O2[0], O2[3]); pwf[256]  = p.x; pwf[PW_OFF+256]  = p.y;
            p = upair(O2[1], O2[2]); pwf[768]  = p.x; pwf[PW_OFF+768]  = p.y;
        } else {
            vf2 p;
            p = upair(O1[0], O2[3]); pwf[tid]      = p.x; pwf[PW_OFF+tid]      = p.y;
            p = upair(O1[1], O2[2]); pwf[tid+512]  = p.x; pwf[PW_OFF+tid+512]  = p.y;
            p = upair(O2[0], O1[3]); pwf[512-tid]  = p.x; pwf[PW_OFF+512-tid]  = p.y;
            p = upair(O2[1], O1[2]); pwf[1024-tid] = p.x; pwf[PW_OFF+1024-tid] = p.y;
        }
    }
    {
        vf2 O1[4], O2[4];
        bf4(B1, O1); bf4(B2, O2);
        float* pwf = pwb + PW_FR;                  // frame B planes (h=1)
        if (tid == 0) {
            vf2 p;
            p = upair(O1[0], O1[0]); pwf[0]    = p.x; pwf[PW_OFF+0]    = p.y;
            p = upair(O1[1], O1[3]); pwf[512]  = p.x; pwf[PW_OFF+512]  = p.y;
            p = upair(O1[2], O1[2]); pwf[1024] = p.x; pwf[PW_OFF+1024] = p.y;
            p = upair(O2[0], O2[3]); pwf[256]  = p.x; pwf[PW_OFF+256]  = p.y;
            p = upair(O2[1], O2[2]); pwf[768]  = p.x; pwf[PW_OFF+768]  = p.y;
        } else {
            vf2 p;
            p = upair(O1[0], O2[3]); pwf[tid]      = p.x; pwf[PW_OFF+tid]      = p.y;
            p = upair(O1[1], O2[2]); pwf[tid+512]  = p.x; pwf[PW_OFF+tid+512]  = p.y;
            p = upair(O2[0], O1[3]); pwf[512-tid]  = p.x; pwf[PW_OFF+512-tid]  = p.y;
            p = upair(O2[1], O1[2]); pwf[1024-tid] = p.x; pwf[PW_OFF+1024-tid] = p.y;
        }
    }
    __syncthreads();

    // ======== Mel projection: thread = (m, frame h); both channels -> float2.
    // Variable-length loop (wn4[m] = 2..15 float4 iters); packed-FMA dot.
    {
        int m  = tid >> 1;
        int h  = tid & 1;                      // frame t0+h
        int a0 = wbeg[m];
        int n4 = wn4[m];
        const float4* wt4 = (const float4*)(wtab + (m << 6));
        const float4* q0  = (const float4*)(pwb + h*PW_FR + a0);           // ch0
        const float4* q1  = (const float4*)(pwb + h*PW_FR + PW_OFF + a0);  // ch1
        vf2 acc0 = (vf2){0.0f, 0.0f};
        vf2 acc1 = (vf2){0.0f, 0.0f};
        for (int j = 0; j < n4; ++j) {
            float4 w4 = wt4[j];
            float4 r0 = q0[j];
            float4 r1 = q1[j];
            vf2 wlo = (vf2){w4.x, w4.y}, whi = (vf2){w4.z, w4.w};
            acc0 += wlo * (vf2){r0.x, r0.y};      // v_pk_fma
            acc0 += whi * (vf2){r0.z, r0.w};
            acc1 += wlo * (vf2){r1.x, r1.y};
            acc1 += whi * (vf2){r1.z, r1.w};
        }
        size_t base = (((size_t)b * N_MELS + m) * T_FRAMES + t0 + h) * CH;
        *(float2*)(out + base) = make_float2(acc0.x + acc0.y, acc1.x + acc1.y);
    }
}

extern "C" void kernel_launch(void* const* d_in, const int* in_sizes, int n_in,
                              void* d_out, int out_size, void* d_ws, size_t ws_size,
                              hipStream_t stream) {
    const float* x  = (const float*)d_in[0];
    const float* fb = (const float*)d_in[1];
    float* out = (float*)d_out;
    float* ws  = (float*)d_ws;

    setup_kernel<<<8 + N_MELS, 256, 0, stream>>>(fb, ws);
    mel_spec_kernel<<<BATCH * (T_FRAMES/2), 256, 0, stream>>>(x, fb, ws, out);
}